// Round 2
// baseline (2584.182 us; speedup 1.0000x reference)
//
#include <hip/hip_runtime.h>
#include <hip/hip_fp16.h>

#define B_SZ 64
#define T_SZ 2048
#define D_SZ 256
#define H_SZ 256
#define G3   768
#define M_SZ (B_SZ * T_SZ) // 131072

typedef _Float16 half2v __attribute__((ext_vector_type(2)));
typedef _Float16 half4v __attribute__((ext_vector_type(4)));
typedef _Float16 half8v __attribute__((ext_vector_type(8)));
typedef float    f32x4  __attribute__((ext_vector_type(4)));

static __device__ __forceinline__ float fdot2f(uint a, uint b, float acc) {
#if __has_builtin(__builtin_amdgcn_fdot2)
  return __builtin_amdgcn_fdot2(__builtin_bit_cast(half2v, a),
                                __builtin_bit_cast(half2v, b), acc, false);
#else
  half2v av = __builtin_bit_cast(half2v, a), bv = __builtin_bit_cast(half2v, b);
  acc = fmaf((float)av[0], (float)bv[0], acc);
  acc = fmaf((float)av[1], (float)bv[1], acc);
  return acc;
#endif
}

static __device__ __forceinline__ float h2f(ushort u) {
  return (float)__builtin_bit_cast(_Float16, u);
}
static __device__ __forceinline__ ushort f2h(float x) {
  return __builtin_bit_cast(ushort, (_Float16)x);
}

// ---------- prep: convert Wx and Wh (f32 -> f16) ----------
__global__ void prep_w(const float* __restrict__ Wx, const float* __restrict__ Wh,
                       ushort* __restrict__ Wxh, ushort* __restrict__ Whh) {
  int i = blockIdx.x * 256 + threadIdx.x;
  if (i < G3 * D_SZ) {
    Wxh[i] = f2h(Wx[i]);
    Whh[i] = f2h(Wh[i]);
  }
}

// ---------- GEMM: xs[m, g] = inputs[m, :] . Wx[g, :] + bx[g], stored f16 ----------
// BM=128, BN=256, K=256 (BK=64 x 4). 256 threads = 4 waves (2x2), wave tile 64x128.
__global__ __launch_bounds__(256) void gemm_x(
    const float* __restrict__ A,   // [M_SZ, 256] f32
    const ushort* __restrict__ Bw, // Wx f16 [768, 256]
    const float* __restrict__ bx,  // [768] f32
    ushort* __restrict__ xs) {     // [M_SZ, 768] f16
  __shared__ _Float16 As[128][72];
  __shared__ _Float16 Bs[256][72];
  const int nt = blockIdx.x, mt = blockIdx.y;
  const int tid = threadIdx.x;
  const int lane = tid & 63, wv = tid >> 6;
  const int wr = (wv >> 1) * 64, wc = (wv & 1) * 128;
  const int l15 = lane & 15, l4 = lane >> 4;
  f32x4 acc[4][8] = {};
  for (int kt = 0; kt < 4; kt++) {
    // stage A tile 128x64 (f32 -> f16): 128*16 float4-slots = 2048 = 8*256
#pragma unroll
    for (int i = 0; i < 8; i++) {
      int f = tid + i * 256;
      int r = f >> 4, c4 = f & 15;
      float4 v = *(const float4*)(A + (size_t)(mt * 128 + r) * D_SZ + kt * 64 + c4 * 4);
      half4v h;
      h[0] = (_Float16)v.x; h[1] = (_Float16)v.y;
      h[2] = (_Float16)v.z; h[3] = (_Float16)v.w;
      *(half4v*)&As[r][c4 * 4] = h;
    }
    // stage B tile 256x64 (f16): 256*8 8-half slots = 2048 = 8*256  [round-1 bug: was i<4]
#pragma unroll
    for (int i = 0; i < 8; i++) {
      int f = tid + i * 256;
      int r = f >> 3, c8 = f & 7;
      uint4 v = *(const uint4*)(Bw + (size_t)(nt * 256 + r) * D_SZ + kt * 64 + c8 * 8);
      *(uint4*)&Bs[r][c8 * 8] = v;
    }
    __syncthreads();
#pragma unroll
    for (int kk = 0; kk < 2; kk++) {
      half8v af[4], bf[8];
#pragma unroll
      for (int m = 0; m < 4; m++)
        af[m] = *(const half8v*)&As[wr + m * 16 + l15][kk * 32 + l4 * 8];
#pragma unroll
      for (int n = 0; n < 8; n++)
        bf[n] = *(const half8v*)&Bs[wc + n * 16 + l15][kk * 32 + l4 * 8];
#pragma unroll
      for (int m = 0; m < 4; m++) {
#pragma unroll
        for (int n = 0; n < 8; n++) {
          acc[m][n] = __builtin_amdgcn_mfma_f32_16x16x32_f16(af[m], bf[n], acc[m][n], 0, 0, 0);
        }
      }
    }
    __syncthreads();
  }
  // epilogue: add bias, store f16
#pragma unroll
  for (int n = 0; n < 8; n++) {
    int col = nt * 256 + wc + n * 16 + l15;
    float bxv = bx[col];
#pragma unroll
    for (int m = 0; m < 4; m++) {
#pragma unroll
      for (int v4 = 0; v4 < 4; v4++) {
        int row = mt * 128 + wr + m * 16 + l4 * 4 + v4;
        xs[(size_t)row * G3 + col] = f2h(acc[m][n][v4] + bxv);
      }
    }
  }
}

// ---------- recurrence: one WG per batch element, 768 threads (12 waves) ----------
// thread j owns pre-activation row j (gate g = j>>8, unit i = j&255).
// Wh row j lives in 128 VGPRs as f16 pairs; h lives in LDS as f16 (uniform
// broadcast reads). Two barriers per step.
__global__ __launch_bounds__(768) void gru_rec(
    const ushort* __restrict__ xs,  // [B, T, 768] f16
    const ushort* __restrict__ Whh, // [768, 256] f16
    const float* __restrict__ bh,   // [768]
    const float* __restrict__ hid,  // [1, B, 256]
    float* __restrict__ out) {      // [B, T, 256] f32
  const int b = blockIdx.x;
  const int j = threadIdx.x;
  __shared__ alignas(16) ushort h16[H_SZ];
  __shared__ float rs[H_SZ];
  __shared__ float us[H_SZ];

  uint w[128];
  {
    const uint4* wp = (const uint4*)(Whh + (size_t)j * D_SZ);
#pragma unroll
    for (int i = 0; i < 32; i++) {
      uint4 q = wp[i];
      w[4 * i + 0] = q.x; w[4 * i + 1] = q.y;
      w[4 * i + 2] = q.z; w[4 * i + 3] = q.w;
    }
  }
  const float bhj = bh[j];
  if (j < H_SZ) h16[j] = f2h(hid[b * H_SZ + j]);
  __syncthreads();

  const ushort* xrow = xs + (size_t)b * T_SZ * G3 + j;
  float* orow = out + (size_t)b * T_SZ * H_SZ;
  ushort xu = xrow[0];

#pragma unroll 1
  for (int t = 0; t < T_SZ; t++) {
    // prefetch next step's x (latency hidden under this step's dot)
    ushort xnext = (t + 1 < T_SZ) ? xrow[(size_t)(t + 1) * G3] : (ushort)0;
    float x = h2f(xu);

    // dot: Wh[j,:] . h  (128 x v_dot2_f32_f16, h broadcast from LDS)
    float d0 = 0.f, d1 = 0.f;
    const uint4* hq = (const uint4*)h16;
#pragma unroll
    for (int c = 0; c < 32; c++) {
      uint4 q = hq[c];
      d0 = fdot2f(w[4 * c + 0], q.x, d0);
      d1 = fdot2f(w[4 * c + 1], q.y, d1);
      d0 = fdot2f(w[4 * c + 2], q.z, d0);
      d1 = fdot2f(w[4 * c + 3], q.w, d1);
    }
    float pre = d0 + d1 + bhj;  // (h @ Wh.T + bh)[j]

    if (j < 512) {
      float a = pre + x;                     // x_r + h_r  |  x_u + h_u
      float s = 1.f / (1.f + __expf(-a));    // sigmoid
      if (j < H_SZ) rs[j] = s;
      else          us[j - H_SZ] = s;
    }
    __syncthreads();

    if (j >= 512) {                          // gate-n threads do the combine
      int i = j - 512;
      float r = rs[i], u = us[i];
      float hold = h2f(h16[i]);
      float arg = x + r * pre;               // x_n + reset*(h_n)
      float e = __expf(-2.f * fabsf(arg));   // stable tanh
      float th = copysignf((1.f - e) / (1.f + e), arg);
      float hn = u * hold + (1.f - u) * th;
      orow[(size_t)t * H_SZ + i] = hn;
      h16[i] = f2h(hn);
    }
    __syncthreads();
    xu = xnext;
  }
}

extern "C" void kernel_launch(void* const* d_in, const int* in_sizes, int n_in,
                              void* d_out, int out_size, void* d_ws, size_t ws_size,
                              hipStream_t stream) {
  const float* inp = (const float*)d_in[0]; // [B,T,D] f32
  const float* hid = (const float*)d_in[1]; // [1,B,H] f32
  const float* Wx  = (const float*)d_in[2]; // [768,256] f32
  const float* bx  = (const float*)d_in[3]; // [768] f32
  const float* Wh  = (const float*)d_in[4]; // [768,256] f32
  const float* bh  = (const float*)d_in[5]; // [768] f32
  float* out = (float*)d_out;

  // workspace layout: xs f16 [M_SZ,768] (~192 MiB), then Wx_f16, Wh_f16
  char* ws = (char*)d_ws;
  ushort* xs = (ushort*)ws;
  size_t xs_bytes = (size_t)M_SZ * G3 * sizeof(ushort);
  ushort* Wxh = (ushort*)(ws + xs_bytes);
  ushort* Whh = Wxh + (size_t)G3 * D_SZ;

  prep_w<<<768, 256, 0, stream>>>(Wx, Wh, Wxh, Whh);
  gemm_x<<<dim3(3, 1024), 256, 0, stream>>>(inp, Wxh, bx, xs);
  gru_rec<<<B_SZ, G3, 0, stream>>>(xs, Whh, bh, hid, out);
}